// Round 3
// baseline (530.300 us; speedup 1.0000x reference)
//
#include <hip/hip_runtime.h>
#include <math.h>
#include <float.h>

#define VOCAB    32000
#define NT       256
#define NWAVES   (NT / 64)
#define CAP      1024    // candidate buffer; E[count]=228 at theta=14, huge headroom
#define KMAX     64      // >= top_k (50)
#define KREF     24.0f   // fixed exp reference point in x units
#define THETA0   14.0f   // collection threshold in x units; 50th-largest ~16.9 +- 0.25

#if __has_builtin(__builtin_amdgcn_exp2f)
  #define EXP2F(x) __builtin_amdgcn_exp2f(x)
#else
  #define EXP2F(x) __expf((x) * 0.6931471805599453f)
#endif

#define LOG2E 1.44269504088896340736f

// One block per row. Single streaming pass over raw logits:
//   - softmax denominator via fast 2^(l*c1 - c2)  (K-referenced, ~1e-6 rel err)
//   - row max of raw logits (fallback guard only)
//   - candidate collection by raw-logit threshold
// Then: exact IEEE x=l/T for candidates only -> stable rank -> top-p prefix
// walk in reference order (accurate expf) -> Gumbel argmax -> outputs.
__global__ __launch_bounds__(NT) void dream_row_kernel(
    const float* __restrict__ logits,
    const float* __restrict__ gumbel,
    const float* __restrict__ tempP,
    const float* __restrict__ toppP,
    const int*   __restrict__ topkP,
    float* __restrict__ out_conf,
    float* __restrict__ out_x0,
    float* __restrict__ out_iconf)
{
    const int row = blockIdx.x;
    const int tid = threadIdx.x;
    const int lane = tid & 63;
    const int wid  = tid >> 6;
    const size_t base = (size_t)row * VOCAB;
    const float4* l4 = (const float4*)(logits + base);
    const float T = tempP[0];
    const float c1 = LOG2E / T;          // one div per thread, negligible
    const float c2 = KREF * LOG2E;
    const float thraw = THETA0 * T;      // raw-logit collection threshold

    __shared__ float s_val[CAP];         // raw logit, later converted to x
    __shared__ int   s_idx[CAP];
    __shared__ int   s_cnt;
    __shared__ float wsum[NWAVES], wmax[NWAVES];
    __shared__ float sh_S, sh_mraw;
    __shared__ float so_val[KMAX];
    __shared__ int   so_idx[KMAX];
    __shared__ int   sh_nk;
    __shared__ float sh_skept;

    if (tid == 0) s_cnt = 0;
    __syncthreads();

    // ---- single fused pass: fast exp2 sum + raw max + candidate collect ----
    float sA = 0.0f, sB = 0.0f;
    float mxr = -FLT_MAX;
    #pragma unroll 4
    for (int j = tid; j < VOCAB / 4; j += NT) {
        float4 v = l4[j];
        sA += EXP2F(fmaf(v.x, c1, -c2));
        sB += EXP2F(fmaf(v.y, c1, -c2));
        sA += EXP2F(fmaf(v.z, c1, -c2));
        sB += EXP2F(fmaf(v.w, c1, -c2));
        mxr = fmaxf(mxr, fmaxf(fmaxf(v.x, v.y), fmaxf(v.z, v.w)));
        int bi = j * 4;
        if (v.x > thraw) { int p = atomicAdd(&s_cnt, 1); if (p < CAP) { s_val[p] = v.x; s_idx[p] = bi;     } }
        if (v.y > thraw) { int p = atomicAdd(&s_cnt, 1); if (p < CAP) { s_val[p] = v.y; s_idx[p] = bi + 1; } }
        if (v.z > thraw) { int p = atomicAdd(&s_cnt, 1); if (p < CAP) { s_val[p] = v.z; s_idx[p] = bi + 2; } }
        if (v.w > thraw) { int p = atomicAdd(&s_cnt, 1); if (p < CAP) { s_val[p] = v.w; s_idx[p] = bi + 3; } }
    }

    // ---- wave-shuffle reduce, then tiny cross-wave combine ----
    float s = sA + sB;
    #pragma unroll
    for (int o = 32; o > 0; o >>= 1) {
        s   += __shfl_down(s, o, 64);
        mxr  = fmaxf(mxr, __shfl_down(mxr, o, 64));
    }
    if (lane == 0) { wsum[wid] = s; wmax[wid] = mxr; }
    __syncthreads();
    if (tid == 0) {
        float St = 0.0f, Mt = -FLT_MAX;
        #pragma unroll
        for (int w = 0; w < NWAVES; ++w) { St += wsum[w]; Mt = fmaxf(Mt, wmax[w]); }
        sh_S = St; sh_mraw = Mt;
    }
    __syncthreads();
    const float S_K = sh_S;
    int C = min(s_cnt, CAP);

    // ---- rare fallback: fixed theta missed — recollect with adaptive theta ----
    if (C < KMAX) {
        if (tid == 0) s_cnt = 0;
        __syncthreads();
        const float th2 = sh_mraw - 12.0f * T;
        for (int j = tid; j < VOCAB / 4; j += NT) {
            float4 v = l4[j];
            int bi = j * 4;
            if (v.x > th2) { int p = atomicAdd(&s_cnt, 1); if (p < CAP) { s_val[p] = v.x; s_idx[p] = bi;     } }
            if (v.y > th2) { int p = atomicAdd(&s_cnt, 1); if (p < CAP) { s_val[p] = v.y; s_idx[p] = bi + 1; } }
            if (v.z > th2) { int p = atomicAdd(&s_cnt, 1); if (p < CAP) { s_val[p] = v.z; s_idx[p] = bi + 2; } }
            if (v.w > th2) { int p = atomicAdd(&s_cnt, 1); if (p < CAP) { s_val[p] = v.w; s_idx[p] = bi + 3; } }
        }
        __syncthreads();
        C = min(s_cnt, CAP);
    }

    // ---- exact IEEE x = l/T for candidates only (ordering must match ref) ----
    for (int c = tid; c < C; c += NT) s_val[c] = s_val[c] / T;
    __syncthreads();

    // ---- rank candidates (stable: value desc, index asc); keep top-KMAX ----
    for (int c = tid; c < C; c += NT) {
        float vc = s_val[c]; int ic = s_idx[c];
        int r = 0;
        for (int j = 0; j < C; ++j) {
            float vj = s_val[j];
            if (vj > vc || (vj == vc && s_idx[j] < ic)) r++;
        }
        if (r < KMAX) { so_val[r] = vc; so_idx[r] = ic; }
    }
    __syncthreads();

    // ---- top-p prefix walk + top-k cap; replicate reference addition order ----
    if (tid == 0) {
        int k = topkP[0]; if (k > KMAX) k = KMAX; if (k < 1) k = 1;
        const float topp = toppP[0];
        const int lim = min(C, k);
        float cum = 0.0f;     // prob mass of ranks before j (full softmax)
        float skept = 0.0f;   // K-referenced masked softmax denominator
        int nk = 0;
        for (int j = 0; j < lim; ++j) {
            if (cum > topp) break;          // rank j removed iff cum_{j-1} > top_p
            float e = expf(so_val[j] - KREF);
            cum += e / S_K;
            skept += e;
            nk++;
        }
        sh_nk = nk;
        sh_skept = skept;
    }
    __syncthreads();
    const int nk = sh_nk;
    const float skept = sh_skept;

    // ---- Gumbel argmax over kept tokens (wave 0 only; first-index tie-break) ----
    if (wid == 0) {
        float bv = -FLT_MAX; int bi = 0x7FFFFFFF; float bx = 0.0f;
        if (lane < nk) {
            int gi = so_idx[lane];
            bx = so_val[lane];
            bv = bx + gumbel[base + gi];
            bi = gi;
        }
        #pragma unroll
        for (int o = 32; o > 0; o >>= 1) {
            float ov = __shfl_down(bv, o, 64);
            int   oi = __shfl_down(bi, o, 64);
            float ox = __shfl_down(bx, o, 64);
            if (ov > bv || (ov == bv && oi < bi)) { bv = ov; bi = oi; bx = ox; }
        }
        if (lane == 0) {
            float confv = expf(bx - KREF) / skept;   // probs[x0] of masked softmax
            out_conf[row]  = confv;
            out_x0[row]    = (float)bi;
            out_iconf[row] = confv;
        }
    }
}

// Global accept step: any(conf > thr) ? per-row high : one-hot at argmax(conf)
__global__ __launch_bounds__(NT) void accept_kernel(
    const float* __restrict__ conf,
    const float* __restrict__ thrP,
    float* __restrict__ acc_out,
    int N)
{
    __shared__ float rv[NT];
    __shared__ int   ri[NT];
    __shared__ int   ra[NT];
    const int tid = threadIdx.x;
    const float thr = thrP[0];

    float bv = -FLT_MAX; int bi = 0x7FFFFFFF; int any = 0;
    for (int i = tid; i < N; i += NT) {
        float v = conf[i];
        if (v > thr) any = 1;
        if (v > bv) { bv = v; bi = i; }   // ascending i -> first occurrence on ties
    }
    rv[tid] = bv; ri[tid] = bi; ra[tid] = any;
    __syncthreads();
    #pragma unroll
    for (int s = NT / 2; s > 0; s >>= 1) {
        if (tid < s) {
            float ov = rv[tid + s]; int oi = ri[tid + s];
            if (ov > rv[tid] || (ov == rv[tid] && oi < ri[tid])) {
                rv[tid] = ov; ri[tid] = oi;
            }
            ra[tid] |= ra[tid + s];
        }
        __syncthreads();
    }
    const int anyHigh = ra[0];
    const int amax = ri[0];
    for (int i = tid; i < N; i += NT) {
        float a;
        if (anyHigh) a = (conf[i] > thr) ? 1.0f : 0.0f;
        else         a = (i == amax) ? 1.0f : 0.0f;
        acc_out[i] = a;
    }
}

extern "C" void kernel_launch(void* const* d_in, const int* in_sizes, int n_in,
                              void* d_out, int out_size, void* d_ws, size_t ws_size,
                              hipStream_t stream)
{
    const float* logits = (const float*)d_in[0];
    const float* gumbel = (const float*)d_in[1];
    const float* tempP  = (const float*)d_in[2];
    const float* toppP  = (const float*)d_in[3];
    const int*   topkP  = (const int*)d_in[4];
    const float* thrP   = (const float*)d_in[5];
    float* out = (float*)d_out;
    const int N = in_sizes[0] / VOCAB;

    dream_row_kernel<<<N, NT, 0, stream>>>(
        logits, gumbel, tempP, toppP, topkP,
        out /*confidence*/, out + N /*x0*/, out + 2 * N /*initial_confidence*/);

    accept_kernel<<<1, NT, 0, stream>>>(
        out, thrP, out + 3 * N /*accepted*/, N);
}